// Round 3
// baseline (267.026 us; speedup 1.0000x reference)
//
#include <hip/hip_runtime.h>
#include <stdint.h>

#define B_ 4
#define C_ 64
#define H_ 96
#define W_ 96
#define HP_ 48
#define WP_ 48
#define N_ (H_*W_)      // 9216
#define M_ (HP_*WP_)    // 2304
#define KD_ 64
#define OD_ 64
#define BN_EPS 1e-5f
#define LOG2E 1.4426950408889634f
#define SHIFT2 28.853900817779268f   // 20 * LOG2E
#define QT_ 32                        // R3: q-tile 48->32 -> grid 1152 = 4.5/CU avg,
                                      // 5 resident (LDS 5*32KB = exactly 160KB)
#define QI_ (QT_/16)                  // 2 q-frags per block
#define QB_ (N_/QT_)                  // 288 q-tiles per batch
#define NT_ (M_/64)                   // 36 m-tiles

typedef __bf16 bf16_t;
typedef bf16_t bf16x8 __attribute__((ext_vector_type(8)));
typedef bf16_t bf16x4 __attribute__((ext_vector_type(4)));
typedef float f32x4 __attribute__((ext_vector_type(4)));
typedef short short4v __attribute__((ext_vector_type(4)));

static __device__ __forceinline__ unsigned short f2bf(float f) {
    unsigned int u = __builtin_bit_cast(unsigned int, f);
    u += 0x7fffu + ((u >> 16) & 1u);
    return (unsigned short)(u >> 16);
}

// Host-safe wrapper (builtin only exists in the device pass; R4/R6 verified
// this MFMA's C/D layout on HW: absmax 0.03125).
static __device__ __forceinline__ f32x4 mfma16_bf16(short4v a, short4v b, f32x4 c) {
#if __has_builtin(__builtin_amdgcn_mfma_f32_16x16x16bf16_1k)
    return __builtin_amdgcn_mfma_f32_16x16x16bf16_1k(a, b, c, 0, 0, 0);
#else
    return c;  // host pass only — never executed on device
#endif
}

// async global->LDS DMA, 16B per lane. LDS dest must be linear
// (wave-uniform base + lane*16); swizzle lives on the GLOBAL source side.
static __device__ __forceinline__ void gl_lds16(const unsigned short* g, unsigned short* l) {
#if __has_builtin(__builtin_amdgcn_global_load_lds)
    __builtin_amdgcn_global_load_lds(
        (const __attribute__((address_space(1))) unsigned int*)(const void*)g,
        (__attribute__((address_space(3))) unsigned int*)(void*)l, 16, 0, 0);
#endif
}

// s_setprio requires a LITERAL constant argument (R1 compile failure).
static __device__ __forceinline__ void setprio1() {
#if __has_builtin(__builtin_amdgcn_s_setprio)
    __builtin_amdgcn_s_setprio(1);
#endif
}
static __device__ __forceinline__ void setprio0() {
#if __has_builtin(__builtin_amdgcn_s_setprio)
    __builtin_amdgcn_s_setprio(0);
#endif
}

// ---------------- Kernel 1: fused pool(x,c2) + key conv + edge attention ----------------
// ea output pre-scaled by LOG2E.
__global__ __launch_bounds__(256) void prep_kernel(
    const float* __restrict__ x, const float* __restrict__ c2,
    const float* __restrict__ wq, const float* __restrict__ bq,
    const float* __restrict__ w1, const float* __restrict__ bnw, const float* __restrict__ bnb,
    const float* __restrict__ bnm, const float* __restrict__ bnv,
    const float* __restrict__ w2, const float* __restrict__ b2,
    unsigned short* __restrict__ kb, unsigned short* __restrict__ vb, float* __restrict__ ea) {

    __shared__ float lw1[OD_*2*C_];
    __shared__ float lwq[KD_*C_];
    __shared__ float xs[C_*33];
    __shared__ float c2s[C_*33];
    __shared__ float red[8][32];

    int tid = threadIdx.x;
    int b = blockIdx.x / 72;
    int m0 = (blockIdx.x % 72) * 32;

    for (int i = tid; i < OD_*2*C_; i += 256) lw1[i] = w1[i];
    for (int i = tid; i < KD_*C_; i += 256) lwq[i] = wq[i];
    for (int j = tid; j < 2048; j += 256) {
        int c = j >> 5, p = j & 31;
        int m = m0 + p;
        int hp = m / WP_, wp = m % WP_;
        size_t base = ((size_t)(b*C_ + c)*H_ + 2*hp)*W_ + 2*wp;
        const float* px = x + base;
        float mx = fmaxf(fmaxf(px[0], px[1]), fmaxf(px[W_], px[W_+1]));
        xs[c*33 + p] = mx;
        vb[(size_t)(b*C_ + c)*M_ + m] = f2bf(mx);
        const float* pc = c2 + base;
        c2s[c*33 + p] = fmaxf(fmaxf(pc[0], pc[1]), fmaxf(pc[W_], pc[W_+1]));
    }
    __syncthreads();

    int ml = tid & 31, oz = tid >> 5;
    int m = m0 + ml;

    float h[8] = {0,0,0,0,0,0,0,0};
    for (int c = 0; c < C_; c += 4) {
        float x0 = xs[c*33+ml], x1 = xs[(c+1)*33+ml], x2 = xs[(c+2)*33+ml], x3 = xs[(c+3)*33+ml];
        #pragma unroll
        for (int oi = 0; oi < 8; oi++) {
            const float4 wv = *(const float4*)&lwq[(oz*8 + oi)*C_ + c];
            h[oi] = fmaf(wv.x, x0, fmaf(wv.y, x1, fmaf(wv.z, x2, fmaf(wv.w, x3, h[oi]))));
        }
    }
    unsigned short tmp[8];
    #pragma unroll
    for (int oi = 0; oi < 8; oi++) tmp[oi] = f2bf(h[oi] + bq[oz*8 + oi]);
    *(uint4*)&kb[((size_t)b*M_ + m)*KD_ + oz*8] = *(const uint4*)tmp;

    float g[8] = {0,0,0,0,0,0,0,0};
    for (int c = 0; c < 2*C_; c += 4) {
        const float* srcb = (c < C_) ? &c2s[c*33] : &xs[(c - C_)*33];
        float x0 = srcb[ml], x1 = srcb[33+ml], x2 = srcb[66+ml], x3 = srcb[99+ml];
        #pragma unroll
        for (int oi = 0; oi < 8; oi++) {
            const float4 wv = *(const float4*)&lw1[(oz*8 + oi)*(2*C_) + c];
            g[oi] = fmaf(wv.x, x0, fmaf(wv.y, x1, fmaf(wv.z, x2, fmaf(wv.w, x3, g[oi]))));
        }
    }
    float z = 0.f;
    #pragma unroll
    for (int oi = 0; oi < 8; oi++) {
        int o = oz*8 + oi;
        float sc = bnw[o] * rsqrtf(bnv[o] + BN_EPS);
        float t = (g[oi] - bnm[o]) * sc + bnb[o];
        z += w2[o] * fmaxf(t, 0.f);
    }
    red[oz][ml] = z;
    __syncthreads();
    if (oz == 0) {
        float s = b2[0];
        #pragma unroll
        for (int i = 0; i < 8; i++) s += red[i][ml];
        ea[(size_t)b*M_ + m] = LOG2E / (1.f + __builtin_amdgcn_exp2f(-s * LOG2E));
    }
}

// ---------------- Kernel 2: query conv at full res -> bf16 [b][n][64] ----------------
__global__ __launch_bounds__(256) void qk_kernel(const float* __restrict__ in, const float* __restrict__ wq,
    const float* __restrict__ bq, unsigned short* __restrict__ outb) {
    __shared__ float lw[KD_*C_];
    for (int i = threadIdx.x; i < KD_*C_; i += 256) lw[i] = wq[i];
    __syncthreads();
    int ml = threadIdx.x & 31, oz = threadIdx.x >> 5;
    int pg = blockIdx.x * 32 + ml;
    float h[8] = {0,0,0,0,0,0,0,0};
    const float* src = in + ((size_t)(pg / N_))*C_*N_ + (pg % N_);
    for (int c = 0; c < C_; c += 4) {
        float x0 = src[(size_t)c*N_], x1 = src[(size_t)(c+1)*N_];
        float x2 = src[(size_t)(c+2)*N_], x3 = src[(size_t)(c+3)*N_];
        #pragma unroll
        for (int oi = 0; oi < 8; oi++) {
            const float4 wv = *(const float4*)&lw[(oz*8 + oi)*C_ + c];
            h[oi] = fmaf(wv.x, x0, fmaf(wv.y, x1, fmaf(wv.z, x2, fmaf(wv.w, x3, h[oi]))));
        }
    }
    unsigned short tmp[8];
    #pragma unroll
    for (int oi = 0; oi < 8; oi++) tmp[oi] = f2bf(h[oi] + bq[oz*8 + oi]);
    *(uint4*)&outb[(size_t)pg*KD_ + oz*8] = *(const uint4*)tmp;
}

// ---------------- Kernel 3: flash attention ----------------
// R3: latency-bound with 12 waves/CU (R2 post-mortem: removing staging work was
// neutral; issue-occupancy ~25% matches 3 waves/SIMD). Fix = more TLP:
// QT 48->32, grid 768->1152 = 4.5 blocks/CU avg, 5 resident
// (5 x 32KB LDS = exactly 160KB; VGPR 72 < 512/5). Staging/barrier work x1.5
// -> L2 ~20 TB/s of 34.5 (why QT=16 was rejected: would need >40 TB/s).
// Structure otherwise identical to R2 (gl_lds DMA + both-sides XOR swizzle,
// setprio around MFMA, ones-MFMA denominator, dbuf 1-barrier/tile).
__global__ __launch_bounds__(256, 5) void attn_kernel(
    const unsigned short* __restrict__ qb, const unsigned short* __restrict__ kb,
    const unsigned short* __restrict__ vb, const float* __restrict__ ea,
    const float* __restrict__ x, const float* __restrict__ gamma_p, float* __restrict__ out) {

    // dbuf: [k 8192 | v 8192] x2 = 32768 B
    // epilogue overlay: o_red 2*32*68*4=17408 + l_red 512 = 17920 B (fits)
    __shared__ __align__(16) char smem[32768];

    int tid = threadIdx.x;
    int wave = tid >> 6, lane = tid & 63, quad = lane >> 4, l16 = lane & 15;
    int blk = blockIdx.x;
    int b = (blk & 7) >> 1;                       // batch pinned to XCD pair
    int n_base = ((blk & 1) * (QB_/2) + (blk >> 3)) * QT_;

    // Q B-frags: B[col = q = qi*16+l16][k = quad*8+j]
    bf16x8 qf[QI_][2];
    #pragma unroll
    for (int qi = 0; qi < QI_; qi++) {
        const unsigned short* qp = qb + ((size_t)b*N_ + n_base + qi*16 + l16)*KD_;
        qf[qi][0] = __builtin_bit_cast(bf16x8, *(const uint4*)(qp + quad*8));
        qf[qi][1] = __builtin_bit_cast(bf16x8, *(const uint4*)(qp + 32 + quad*8));
    }

    f32x4 o2[QI_][4]; // O^T partial: [qi][ct]; D: row=c=ct*16+quad*4+r, col=q=qi*16+l16
    f32x4 lacc[QI_];  // denominator partials via ones-MFMA (all D rows identical)
    #pragma unroll
    for (int qi = 0; qi < QI_; qi++) {
        lacc[qi] = (f32x4){0.f,0.f,0.f,0.f};
        #pragma unroll
        for (int ct = 0; ct < 4; ct++) o2[qi][ct] = (f32x4){0.f,0.f,0.f,0.f};
    }
    const short one_bf = (short)0x3F80;  // bf16 1.0
    short4v ones = (short4v){one_bf, one_bf, one_bf, one_bf};

    const unsigned short* kbB = kb + (size_t)b*M_*KD_;
    const unsigned short* vbB = vb + (size_t)b*C_*M_;
    const float* eaB = ea + (size_t)b*M_;

    // staging thread mapping: row = p*32 + (tid>>3), chunk = tid&7.
    // (row+32)&7 == row&7, so the swizzled source chunk offset is per-thread const.
    int srow = tid >> 3;                    // 0..31
    int ksw  = ((tid & 7) ^ (srow & 7)) << 3;  // swizzled src offset (shorts)

    // DMA-stage one 64-m tile (K: 64x64 bf16 row-major; V: 64c x 64m bf16)
    auto STAGE = [&](int mb, char* kd, char* vd) {
        unsigned short* kds = (unsigned short*)kd;
        unsigned short* vds = (unsigned short*)vd;
        gl_lds16(kbB + (size_t)(mb + srow)*KD_      + ksw, kds + tid*8);
        gl_lds16(kbB + (size_t)(mb + srow + 32)*KD_ + ksw, kds + 2048 + tid*8);
        gl_lds16(vbB + (size_t)srow*M_      + mb + ksw, vds + tid*8);
        gl_lds16(vbB + (size_t)(srow+32)*M_ + mb + ksw, vds + 2048 + tid*8);
    };

    // prologue: stage tile 0 into buffer 0 (barrier drains vmcnt)
    STAGE(0, smem, smem + 8192);
    __syncthreads();

    int xsw = l16 & 7;   // row&7 for all frag rows this lane touches (rows are l16 mod 16)

    for (int mt = 0; mt < NT_; mt++) {
        int cur = mt & 1;
        if (mt < NT_ - 1) {
            char* nb = smem + (1 - cur)*16384;
            STAGE((mt+1)*64, nb, nb + 8192);   // async, in flight across this tile
        }
        unsigned short* kc = (unsigned short*)(smem + cur*16384);
        unsigned short* vc = (unsigned short*)(smem + cur*16384 + 8192);

        // ea broadcast for this wave's strip (L1-served, 4 distinct addrs/wave)
        f32x4 e4 = *(const f32x4*)(eaB + mt*64 + wave*16 + quad*4);

        // K A-frag + V A-frags up front (swizzled chunk index: cg ^ (row&7))
        int krow = wave*16 + l16;
        bf16x8 kf0 = __builtin_bit_cast(bf16x8, *(const uint4*)(kc + krow*KD_ + (((quad  ) ^ xsw) << 3)));
        bf16x8 kf1 = __builtin_bit_cast(bf16x8, *(const uint4*)(kc + krow*KD_ + (((quad+4) ^ xsw) << 3)));
        short4v va[4];
        #pragma unroll
        for (int ct = 0; ct < 4; ct++)
            va[ct] = *(const short4v*)(vc + (ct*16 + l16)*64
                        + (((wave*2 + (quad>>1)) ^ xsw) << 3) + (quad&1)*4);

        // S^T strip: D[m_local = quad*4+r][q = qi*16+l16]
        f32x4 st[QI_];
        setprio1();
        #pragma unroll
        for (int qi = 0; qi < QI_; qi++) {
            f32x4 z = (f32x4){0.f,0.f,0.f,0.f};
            z = __builtin_amdgcn_mfma_f32_16x16x32_bf16(kf0, qf[qi][0], z, 0, 0, 0);
            z = __builtin_amdgcn_mfma_f32_16x16x32_bf16(kf1, qf[qi][1], z, 0, 0, 0);
            st[qi] = z;
        }
        setprio0();

        // fixed-shift softmax numerators; packed cvt (v_cvt_pk_bf16_f32)
        short4v pk[QI_];
        #pragma unroll
        for (int qi = 0; qi < QI_; qi++) {
            f32x4 p;
            p[0] = __builtin_amdgcn_exp2f(fmaf(st[qi][0], e4[0], -SHIFT2));
            p[1] = __builtin_amdgcn_exp2f(fmaf(st[qi][1], e4[1], -SHIFT2));
            p[2] = __builtin_amdgcn_exp2f(fmaf(st[qi][2], e4[2], -SHIFT2));
            p[3] = __builtin_amdgcn_exp2f(fmaf(st[qi][3], e4[3], -SHIFT2));
            pk[qi] = __builtin_bit_cast(short4v, __builtin_convertvector(p, bf16x4));
        }

        // PV (A = V^T strip frag, B = P) + denominator via ones-A MFMA
        setprio1();
        #pragma unroll
        for (int ct = 0; ct < 4; ct++)
            #pragma unroll
            for (int qi = 0; qi < QI_; qi++)
                o2[qi][ct] = mfma16_bf16(va[ct], pk[qi], o2[qi][ct]);
        #pragma unroll
        for (int qi = 0; qi < QI_; qi++)
            lacc[qi] = mfma16_bf16(ones, pk[qi], lacc[qi]);
        setprio0();

        __syncthreads();   // compiler drains vmcnt(0) here -> next buffer ready
    }

    // ---- epilogue: cross-wave reduction of O^T partials and denominators ----
    float* o_red0 = (float*)smem;            // [32 q][68 c]
    float* o_red1 = o_red0 + QT_*68;
    float* l_red  = o_red1 + QT_*68;         // [4][32]

    if (lane < 16) {
        #pragma unroll
        for (int qi = 0; qi < QI_; qi++) l_red[wave*QT_ + qi*16 + l16] = lacc[qi][0];
    }
    if (wave < 2) {
        float* od = (wave == 0) ? o_red0 : o_red1;
        #pragma unroll
        for (int qi = 0; qi < QI_; qi++)
            #pragma unroll
            for (int ct = 0; ct < 4; ct++)
                *(f32x4*)&od[(qi*16 + l16)*68 + ct*16 + quad*4] = o2[qi][ct];
    }
    __syncthreads();
    if (wave >= 2) {
        float* od = (wave == 2) ? o_red0 : o_red1;
        #pragma unroll
        for (int qi = 0; qi < QI_; qi++)
            #pragma unroll
            for (int ct = 0; ct < 4; ct++) {
                f32x4* p = (f32x4*)&od[(qi*16 + l16)*68 + ct*16 + quad*4];
                *p += o2[qi][ct];
            }
    }
    __syncthreads();
    if (tid < QT_) {
        float s = (l_red[tid] + l_red[QT_ + tid]) + (l_red[2*QT_ + tid] + l_red[3*QT_ + tid]);
        l_red[tid] = 1.f / s;
    }
    __syncthreads();

    float gmm = gamma_p[0];
    int c = tid >> 2, q4 = tid & 3;
    const float* xrow = x + ((size_t)b*C_ + c)*N_ + n_base;
    float* orow = out + ((size_t)b*C_ + c)*N_ + n_base;
    #pragma unroll
    for (int i = 0; i < QI_; i++) {
        int q0 = q4*4 + i*16;
        float4 xv = *(const float4*)(xrow + q0);
        float4 ov;
        float v0 = (o_red0[(q0+0)*68 + c] + o_red1[(q0+0)*68 + c]) * l_red[q0+0];
        float v1 = (o_red0[(q0+1)*68 + c] + o_red1[(q0+1)*68 + c]) * l_red[q0+1];
        float v2 = (o_red0[(q0+2)*68 + c] + o_red1[(q0+2)*68 + c]) * l_red[q0+2];
        float v3 = (o_red0[(q0+3)*68 + c] + o_red1[(q0+3)*68 + c]) * l_red[q0+3];
        ov.x = fmaf(gmm, v0, xv.x);
        ov.y = fmaf(gmm, v1, xv.y);
        ov.z = fmaf(gmm, v2, xv.z);
        ov.w = fmaf(gmm, v3, xv.w);
        *(float4*)(orow + q0) = ov;
    }
}

extern "C" void kernel_launch(void* const* d_in, const int* in_sizes, int n_in,
                              void* d_out, int out_size, void* d_ws, size_t ws_size,
                              hipStream_t stream) {
    const float* c2    = (const float*)d_in[0];
    const float* x     = (const float*)d_in[1];
    const float* w_ea1 = (const float*)d_in[2];
    const float* bn_w  = (const float*)d_in[3];
    const float* bn_b  = (const float*)d_in[4];
    const float* bn_m  = (const float*)d_in[5];
    const float* bn_v  = (const float*)d_in[6];
    const float* w_ea2 = (const float*)d_in[7];
    const float* b_ea2 = (const float*)d_in[8];
    const float* w_q   = (const float*)d_in[9];
    const float* b_q   = (const float*)d_in[10];
    const float* gamma = (const float*)d_in[11];
    float* out = (float*)d_out;

    char* ws = (char*)d_ws;
    float* ea            = (float*)(ws + 0);                // 36864
    unsigned short* qb   = (unsigned short*)(ws + 36864);   // 4718592
    unsigned short* kb   = (unsigned short*)(ws + 4755456); // 1179648
    unsigned short* vb   = (unsigned short*)(ws + 5935104); // 1179648

    prep_kernel<<<dim3((B_*M_)/32), dim3(256), 0, stream>>>(x, c2, w_q, b_q,
        w_ea1, bn_w, bn_b, bn_m, bn_v, w_ea2, b_ea2, kb, vb, ea);
    qk_kernel<<<dim3((B_*N_)/32), dim3(256), 0, stream>>>(x, w_q, b_q, qb);
    attn_kernel<<<dim3(B_*QB_), dim3(256), 0, stream>>>(qb, kb, vb, ea, x, gamma, out);
}

// Round 4
// 175.535 us; speedup vs baseline: 1.5212x; 1.5212x over previous
//
#include <hip/hip_runtime.h>
#include <stdint.h>

#define B_ 4
#define C_ 64
#define H_ 96
#define W_ 96
#define HP_ 48
#define WP_ 48
#define N_ (H_*W_)      // 9216
#define M_ (HP_*WP_)    // 2304
#define KD_ 64
#define OD_ 64
#define BN_EPS 1e-5f
#define LOG2E 1.4426950408889634f
#define SHIFT2 28.853900817779268f   // 20 * LOG2E
#define QT_ 32                        // q-tile 32 -> grid 1152 = 4.5/CU avg
#define QI_ (QT_/16)                  // 2 q-frags per block
#define QB_ (N_/QT_)                  // 288 q-tiles per batch
#define NT_ (M_/64)                   // 36 m-tiles

typedef __bf16 bf16_t;
typedef bf16_t bf16x8 __attribute__((ext_vector_type(8)));
typedef bf16_t bf16x4 __attribute__((ext_vector_type(4)));
typedef float f32x4 __attribute__((ext_vector_type(4)));
typedef short short4v __attribute__((ext_vector_type(4)));

static __device__ __forceinline__ unsigned short f2bf(float f) {
    unsigned int u = __builtin_bit_cast(unsigned int, f);
    u += 0x7fffu + ((u >> 16) & 1u);
    return (unsigned short)(u >> 16);
}

// Host-safe wrapper (builtin only exists in the device pass; R4/R6 verified
// this MFMA's C/D layout on HW: absmax 0.03125).
static __device__ __forceinline__ f32x4 mfma16_bf16(short4v a, short4v b, f32x4 c) {
#if __has_builtin(__builtin_amdgcn_mfma_f32_16x16x16bf16_1k)
    return __builtin_amdgcn_mfma_f32_16x16x16bf16_1k(a, b, c, 0, 0, 0);
#else
    return c;  // host pass only — never executed on device
#endif
}

// async global->LDS DMA, 16B per lane. LDS dest must be linear
// (wave-uniform base + lane*16); swizzle lives on the GLOBAL source side.
static __device__ __forceinline__ void gl_lds16(const unsigned short* g, unsigned short* l) {
#if __has_builtin(__builtin_amdgcn_global_load_lds)
    __builtin_amdgcn_global_load_lds(
        (const __attribute__((address_space(1))) unsigned int*)(const void*)g,
        (__attribute__((address_space(3))) unsigned int*)(void*)l, 16, 0, 0);
#endif
}

// s_setprio requires a LITERAL constant argument (R1 compile failure).
static __device__ __forceinline__ void setprio1() {
#if __has_builtin(__builtin_amdgcn_s_setprio)
    __builtin_amdgcn_s_setprio(1);
#endif
}
static __device__ __forceinline__ void setprio0() {
#if __has_builtin(__builtin_amdgcn_s_setprio)
    __builtin_amdgcn_s_setprio(0);
#endif
}

// ---------------- Kernel 1: fused pool(x,c2) + key conv + edge attention ----------------
// ea output pre-scaled by LOG2E.
__global__ __launch_bounds__(256) void prep_kernel(
    const float* __restrict__ x, const float* __restrict__ c2,
    const float* __restrict__ wq, const float* __restrict__ bq,
    const float* __restrict__ w1, const float* __restrict__ bnw, const float* __restrict__ bnb,
    const float* __restrict__ bnm, const float* __restrict__ bnv,
    const float* __restrict__ w2, const float* __restrict__ b2,
    unsigned short* __restrict__ kb, unsigned short* __restrict__ vb, float* __restrict__ ea) {

    __shared__ float lw1[OD_*2*C_];
    __shared__ float lwq[KD_*C_];
    __shared__ float xs[C_*33];
    __shared__ float c2s[C_*33];
    __shared__ float red[8][32];

    int tid = threadIdx.x;
    int b = blockIdx.x / 72;
    int m0 = (blockIdx.x % 72) * 32;

    for (int i = tid; i < OD_*2*C_; i += 256) lw1[i] = w1[i];
    for (int i = tid; i < KD_*C_; i += 256) lwq[i] = wq[i];
    for (int j = tid; j < 2048; j += 256) {
        int c = j >> 5, p = j & 31;
        int m = m0 + p;
        int hp = m / WP_, wp = m % WP_;
        size_t base = ((size_t)(b*C_ + c)*H_ + 2*hp)*W_ + 2*wp;
        const float* px = x + base;
        float mx = fmaxf(fmaxf(px[0], px[1]), fmaxf(px[W_], px[W_+1]));
        xs[c*33 + p] = mx;
        vb[(size_t)(b*C_ + c)*M_ + m] = f2bf(mx);
        const float* pc = c2 + base;
        c2s[c*33 + p] = fmaxf(fmaxf(pc[0], pc[1]), fmaxf(pc[W_], pc[W_+1]));
    }
    __syncthreads();

    int ml = tid & 31, oz = tid >> 5;
    int m = m0 + ml;

    float h[8] = {0,0,0,0,0,0,0,0};
    for (int c = 0; c < C_; c += 4) {
        float x0 = xs[c*33+ml], x1 = xs[(c+1)*33+ml], x2 = xs[(c+2)*33+ml], x3 = xs[(c+3)*33+ml];
        #pragma unroll
        for (int oi = 0; oi < 8; oi++) {
            const float4 wv = *(const float4*)&lwq[(oz*8 + oi)*C_ + c];
            h[oi] = fmaf(wv.x, x0, fmaf(wv.y, x1, fmaf(wv.z, x2, fmaf(wv.w, x3, h[oi]))));
        }
    }
    unsigned short tmp[8];
    #pragma unroll
    for (int oi = 0; oi < 8; oi++) tmp[oi] = f2bf(h[oi] + bq[oz*8 + oi]);
    *(uint4*)&kb[((size_t)b*M_ + m)*KD_ + oz*8] = *(const uint4*)tmp;

    float g[8] = {0,0,0,0,0,0,0,0};
    for (int c = 0; c < 2*C_; c += 4) {
        const float* srcb = (c < C_) ? &c2s[c*33] : &xs[(c - C_)*33];
        float x0 = srcb[ml], x1 = srcb[33+ml], x2 = srcb[66+ml], x3 = srcb[99+ml];
        #pragma unroll
        for (int oi = 0; oi < 8; oi++) {
            const float4 wv = *(const float4*)&lw1[(oz*8 + oi)*(2*C_) + c];
            g[oi] = fmaf(wv.x, x0, fmaf(wv.y, x1, fmaf(wv.z, x2, fmaf(wv.w, x3, g[oi]))));
        }
    }
    float z = 0.f;
    #pragma unroll
    for (int oi = 0; oi < 8; oi++) {
        int o = oz*8 + oi;
        float sc = bnw[o] * rsqrtf(bnv[o] + BN_EPS);
        float t = (g[oi] - bnm[o]) * sc + bnb[o];
        z += w2[o] * fmaxf(t, 0.f);
    }
    red[oz][ml] = z;
    __syncthreads();
    if (oz == 0) {
        float s = b2[0];
        #pragma unroll
        for (int i = 0; i < 8; i++) s += red[i][ml];
        ea[(size_t)b*M_ + m] = LOG2E / (1.f + __builtin_amdgcn_exp2f(-s * LOG2E));
    }
}

// ---------------- Kernel 2: query conv at full res -> bf16 [b][n][64] ----------------
__global__ __launch_bounds__(256) void qk_kernel(const float* __restrict__ in, const float* __restrict__ wq,
    const float* __restrict__ bq, unsigned short* __restrict__ outb) {
    __shared__ float lw[KD_*C_];
    for (int i = threadIdx.x; i < KD_*C_; i += 256) lw[i] = wq[i];
    __syncthreads();
    int ml = threadIdx.x & 31, oz = threadIdx.x >> 5;
    int pg = blockIdx.x * 32 + ml;
    float h[8] = {0,0,0,0,0,0,0,0};
    const float* src = in + ((size_t)(pg / N_))*C_*N_ + (pg % N_);
    for (int c = 0; c < C_; c += 4) {
        float x0 = src[(size_t)c*N_], x1 = src[(size_t)(c+1)*N_];
        float x2 = src[(size_t)(c+2)*N_], x3 = src[(size_t)(c+3)*N_];
        #pragma unroll
        for (int oi = 0; oi < 8; oi++) {
            const float4 wv = *(const float4*)&lw[(oz*8 + oi)*C_ + c];
            h[oi] = fmaf(wv.x, x0, fmaf(wv.y, x1, fmaf(wv.z, x2, fmaf(wv.w, x3, h[oi]))));
        }
    }
    unsigned short tmp[8];
    #pragma unroll
    for (int oi = 0; oi < 8; oi++) tmp[oi] = f2bf(h[oi] + bq[oz*8 + oi]);
    *(uint4*)&outb[(size_t)pg*KD_ + oz*8] = *(const uint4*)tmp;
}

// ---------------- Kernel 3: flash attention ----------------
// R4: clean TLP retest. R3's launch_bounds(256,5) caused VGPR 48 + scratch
// spills (WRITE_SIZE 9.2->27.5 MB) — it measured spill cost, not TLP.
// Here: QT=32, grid 1152, launch_bounds(256,4): VGPR cap 128 (kernel needs
// ~70 -> no spills), 4 resident blocks/CU (LDS 4x32KB=128KB <= 160KB)
// = 16 waves/CU vs R2's 12. Structure otherwise identical to R2
// (gl_lds DMA + both-sides XOR swizzle, setprio, ones-MFMA denom, dbuf).
__global__ __launch_bounds__(256, 4) void attn_kernel(
    const unsigned short* __restrict__ qb, const unsigned short* __restrict__ kb,
    const unsigned short* __restrict__ vb, const float* __restrict__ ea,
    const float* __restrict__ x, const float* __restrict__ gamma_p, float* __restrict__ out) {

    // dbuf: [k 8192 | v 8192] x2 = 32768 B
    // epilogue overlay: o_red 2*32*68*4=17408 + l_red 512 = 17920 B (fits)
    __shared__ __align__(16) char smem[32768];

    int tid = threadIdx.x;
    int wave = tid >> 6, lane = tid & 63, quad = lane >> 4, l16 = lane & 15;
    int blk = blockIdx.x;
    int b = (blk & 7) >> 1;                       // batch pinned to XCD pair
    int n_base = ((blk & 1) * (QB_/2) + (blk >> 3)) * QT_;

    // Q B-frags: B[col = q = qi*16+l16][k = quad*8+j]
    bf16x8 qf[QI_][2];
    #pragma unroll
    for (int qi = 0; qi < QI_; qi++) {
        const unsigned short* qp = qb + ((size_t)b*N_ + n_base + qi*16 + l16)*KD_;
        qf[qi][0] = __builtin_bit_cast(bf16x8, *(const uint4*)(qp + quad*8));
        qf[qi][1] = __builtin_bit_cast(bf16x8, *(const uint4*)(qp + 32 + quad*8));
    }

    f32x4 o2[QI_][4]; // O^T partial: [qi][ct]; D: row=c=ct*16+quad*4+r, col=q=qi*16+l16
    f32x4 lacc[QI_];  // denominator partials via ones-MFMA (all D rows identical)
    #pragma unroll
    for (int qi = 0; qi < QI_; qi++) {
        lacc[qi] = (f32x4){0.f,0.f,0.f,0.f};
        #pragma unroll
        for (int ct = 0; ct < 4; ct++) o2[qi][ct] = (f32x4){0.f,0.f,0.f,0.f};
    }
    const short one_bf = (short)0x3F80;  // bf16 1.0
    short4v ones = (short4v){one_bf, one_bf, one_bf, one_bf};

    const unsigned short* kbB = kb + (size_t)b*M_*KD_;
    const unsigned short* vbB = vb + (size_t)b*C_*M_;
    const float* eaB = ea + (size_t)b*M_;

    // staging thread mapping: row = p*32 + (tid>>3), chunk = tid&7.
    // (row+32)&7 == row&7, so the swizzled source chunk offset is per-thread const.
    int srow = tid >> 3;                    // 0..31
    int ksw  = ((tid & 7) ^ (srow & 7)) << 3;  // swizzled src offset (shorts)

    // DMA-stage one 64-m tile (K: 64x64 bf16 row-major; V: 64c x 64m bf16)
    auto STAGE = [&](int mb, char* kd, char* vd) {
        unsigned short* kds = (unsigned short*)kd;
        unsigned short* vds = (unsigned short*)vd;
        gl_lds16(kbB + (size_t)(mb + srow)*KD_      + ksw, kds + tid*8);
        gl_lds16(kbB + (size_t)(mb + srow + 32)*KD_ + ksw, kds + 2048 + tid*8);
        gl_lds16(vbB + (size_t)srow*M_      + mb + ksw, vds + tid*8);
        gl_lds16(vbB + (size_t)(srow+32)*M_ + mb + ksw, vds + 2048 + tid*8);
    };

    // prologue: stage tile 0 into buffer 0 (barrier drains vmcnt)
    STAGE(0, smem, smem + 8192);
    __syncthreads();

    int xsw = l16 & 7;   // row&7 for all frag rows this lane touches (rows are l16 mod 16)

    for (int mt = 0; mt < NT_; mt++) {
        int cur = mt & 1;
        if (mt < NT_ - 1) {
            char* nb = smem + (1 - cur)*16384;
            STAGE((mt+1)*64, nb, nb + 8192);   // async, in flight across this tile
        }
        unsigned short* kc = (unsigned short*)(smem + cur*16384);
        unsigned short* vc = (unsigned short*)(smem + cur*16384 + 8192);

        // ea broadcast for this wave's strip (L1-served, 4 distinct addrs/wave)
        f32x4 e4 = *(const f32x4*)(eaB + mt*64 + wave*16 + quad*4);

        // K A-frag + V A-frags up front (swizzled chunk index: cg ^ (row&7))
        int krow = wave*16 + l16;
        bf16x8 kf0 = __builtin_bit_cast(bf16x8, *(const uint4*)(kc + krow*KD_ + (((quad  ) ^ xsw) << 3)));
        bf16x8 kf1 = __builtin_bit_cast(bf16x8, *(const uint4*)(kc + krow*KD_ + (((quad+4) ^ xsw) << 3)));
        short4v va[4];
        #pragma unroll
        for (int ct = 0; ct < 4; ct++)
            va[ct] = *(const short4v*)(vc + (ct*16 + l16)*64
                        + (((wave*2 + (quad>>1)) ^ xsw) << 3) + (quad&1)*4);

        // S^T strip: D[m_local = quad*4+r][q = qi*16+l16]
        f32x4 st[QI_];
        setprio1();
        #pragma unroll
        for (int qi = 0; qi < QI_; qi++) {
            f32x4 z = (f32x4){0.f,0.f,0.f,0.f};
            z = __builtin_amdgcn_mfma_f32_16x16x32_bf16(kf0, qf[qi][0], z, 0, 0, 0);
            z = __builtin_amdgcn_mfma_f32_16x16x32_bf16(kf1, qf[qi][1], z, 0, 0, 0);
            st[qi] = z;
        }
        setprio0();

        // fixed-shift softmax numerators; packed cvt (v_cvt_pk_bf16_f32)
        short4v pk[QI_];
        #pragma unroll
        for (int qi = 0; qi < QI_; qi++) {
            f32x4 p;
            p[0] = __builtin_amdgcn_exp2f(fmaf(st[qi][0], e4[0], -SHIFT2));
            p[1] = __builtin_amdgcn_exp2f(fmaf(st[qi][1], e4[1], -SHIFT2));
            p[2] = __builtin_amdgcn_exp2f(fmaf(st[qi][2], e4[2], -SHIFT2));
            p[3] = __builtin_amdgcn_exp2f(fmaf(st[qi][3], e4[3], -SHIFT2));
            pk[qi] = __builtin_bit_cast(short4v, __builtin_convertvector(p, bf16x4));
        }

        // PV (A = V^T strip frag, B = P) + denominator via ones-A MFMA
        setprio1();
        #pragma unroll
        for (int ct = 0; ct < 4; ct++)
            #pragma unroll
            for (int qi = 0; qi < QI_; qi++)
                o2[qi][ct] = mfma16_bf16(va[ct], pk[qi], o2[qi][ct]);
        #pragma unroll
        for (int qi = 0; qi < QI_; qi++)
            lacc[qi] = mfma16_bf16(ones, pk[qi], lacc[qi]);
        setprio0();

        __syncthreads();   // compiler drains vmcnt(0) here -> next buffer ready
    }

    // ---- epilogue: cross-wave reduction of O^T partials and denominators ----
    float* o_red0 = (float*)smem;            // [32 q][68 c]
    float* o_red1 = o_red0 + QT_*68;
    float* l_red  = o_red1 + QT_*68;         // [4][32]

    if (lane < 16) {
        #pragma unroll
        for (int qi = 0; qi < QI_; qi++) l_red[wave*QT_ + qi*16 + l16] = lacc[qi][0];
    }
    if (wave < 2) {
        float* od = (wave == 0) ? o_red0 : o_red1;
        #pragma unroll
        for (int qi = 0; qi < QI_; qi++)
            #pragma unroll
            for (int ct = 0; ct < 4; ct++)
                *(f32x4*)&od[(qi*16 + l16)*68 + ct*16 + quad*4] = o2[qi][ct];
    }
    __syncthreads();
    if (wave >= 2) {
        float* od = (wave == 2) ? o_red0 : o_red1;
        #pragma unroll
        for (int qi = 0; qi < QI_; qi++)
            #pragma unroll
            for (int ct = 0; ct < 4; ct++) {
                f32x4* p = (f32x4*)&od[(qi*16 + l16)*68 + ct*16 + quad*4];
                *p += o2[qi][ct];
            }
    }
    __syncthreads();
    if (tid < QT_) {
        float s = (l_red[tid] + l_red[QT_ + tid]) + (l_red[2*QT_ + tid] + l_red[3*QT_ + tid]);
        l_red[tid] = 1.f / s;
    }
    __syncthreads();

    float gmm = gamma_p[0];
    int c = tid >> 2, q4 = tid & 3;
    const float* xrow = x + ((size_t)b*C_ + c)*N_ + n_base;
    float* orow = out + ((size_t)b*C_ + c)*N_ + n_base;
    #pragma unroll
    for (int i = 0; i < QI_; i++) {
        int q0 = q4*4 + i*16;
        float4 xv = *(const float4*)(xrow + q0);
        float4 ov;
        float v0 = (o_red0[(q0+0)*68 + c] + o_red1[(q0+0)*68 + c]) * l_red[q0+0];
        float v1 = (o_red0[(q0+1)*68 + c] + o_red1[(q0+1)*68 + c]) * l_red[q0+1];
        float v2 = (o_red0[(q0+2)*68 + c] + o_red1[(q0+2)*68 + c]) * l_red[q0+2];
        float v3 = (o_red0[(q0+3)*68 + c] + o_red1[(q0+3)*68 + c]) * l_red[q0+3];
        ov.x = fmaf(gmm, v0, xv.x);
        ov.y = fmaf(gmm, v1, xv.y);
        ov.z = fmaf(gmm, v2, xv.z);
        ov.w = fmaf(gmm, v3, xv.w);
        *(float4*)(orow + q0) = ov;
    }
}

extern "C" void kernel_launch(void* const* d_in, const int* in_sizes, int n_in,
                              void* d_out, int out_size, void* d_ws, size_t ws_size,
                              hipStream_t stream) {
    const float* c2    = (const float*)d_in[0];
    const float* x     = (const float*)d_in[1];
    const float* w_ea1 = (const float*)d_in[2];
    const float* bn_w  = (const float*)d_in[3];
    const float* bn_b  = (const float*)d_in[4];
    const float* bn_m  = (const float*)d_in[5];
    const float* bn_v  = (const float*)d_in[6];
    const float* w_ea2 = (const float*)d_in[7];
    const float* b_ea2 = (const float*)d_in[8];
    const float* w_q   = (const float*)d_in[9];
    const float* b_q   = (const float*)d_in[10];
    const float* gamma = (const float*)d_in[11];
    float* out = (float*)d_out;

    char* ws = (char*)d_ws;
    float* ea            = (float*)(ws + 0);                // 36864
    unsigned short* qb   = (unsigned short*)(ws + 36864);   // 4718592
    unsigned short* kb   = (unsigned short*)(ws + 4755456); // 1179648
    unsigned short* vb   = (unsigned short*)(ws + 5935104); // 1179648

    prep_kernel<<<dim3((B_*M_)/32), dim3(256), 0, stream>>>(x, c2, w_q, b_q,
        w_ea1, bn_w, bn_b, bn_m, bn_v, w_ea2, b_ea2, kb, vb, ea);
    qk_kernel<<<dim3((B_*N_)/32), dim3(256), 0, stream>>>(x, w_q, b_q, qb);
    attn_kernel<<<dim3(B_*QB_), dim3(256), 0, stream>>>(qb, kb, vb, ea, x, gamma, out);
}

// Round 5
// 163.139 us; speedup vs baseline: 1.6368x; 1.0760x over previous
//
#include <hip/hip_runtime.h>
#include <stdint.h>

#define B_ 4
#define C_ 64
#define H_ 96
#define W_ 96
#define HP_ 48
#define WP_ 48
#define N_ (H_*W_)      // 9216
#define M_ (HP_*WP_)    // 2304
#define KD_ 64
#define OD_ 64
#define BN_EPS 1e-5f
#define LOG2E 1.4426950408889634f
#define SHIFT2 28.853900817779268f   // 20 * LOG2E
#define QT_ 48                        // q-tile: 768 blocks = exactly 3/CU (best step count)
#define QI_ (QT_/16)                  // 3 q-frags per block
#define QB_ (N_/QT_)                  // 192 q-tiles per batch
#define NT_ (M_/64)                   // 36 m-tiles

typedef __bf16 bf16_t;
typedef bf16_t bf16x8 __attribute__((ext_vector_type(8)));
typedef bf16_t bf16x4 __attribute__((ext_vector_type(4)));
typedef float f32x4 __attribute__((ext_vector_type(4)));
typedef short short4v __attribute__((ext_vector_type(4)));

static __device__ __forceinline__ unsigned short f2bf(float f) {
    unsigned int u = __builtin_bit_cast(unsigned int, f);
    u += 0x7fffu + ((u >> 16) & 1u);
    return (unsigned short)(u >> 16);
}

// Host-safe wrapper (builtin only exists in the device pass).
static __device__ __forceinline__ f32x4 mfma16_bf16(short4v a, short4v b, f32x4 c) {
#if __has_builtin(__builtin_amdgcn_mfma_f32_16x16x16bf16_1k)
    return __builtin_amdgcn_mfma_f32_16x16x16bf16_1k(a, b, c, 0, 0, 0);
#else
    return c;  // host pass only — never executed on device
#endif
}

// async global->LDS DMA, 16B per lane. LDS dest must be linear
// (wave-uniform base + lane*16); swizzle lives on the GLOBAL source side.
static __device__ __forceinline__ void gl_lds16(const unsigned short* g, unsigned short* l) {
#if __has_builtin(__builtin_amdgcn_global_load_lds)
    __builtin_amdgcn_global_load_lds(
        (const __attribute__((address_space(1))) unsigned int*)(const void*)g,
        (__attribute__((address_space(3))) unsigned int*)(void*)l, 16, 0, 0);
#endif
}

// s_setprio requires a LITERAL constant argument.
static __device__ __forceinline__ void setprio1() {
#if __has_builtin(__builtin_amdgcn_s_setprio)
    __builtin_amdgcn_s_setprio(1);
#endif
}
static __device__ __forceinline__ void setprio0() {
#if __has_builtin(__builtin_amdgcn_s_setprio)
    __builtin_amdgcn_s_setprio(0);
#endif
}
static __device__ __forceinline__ void schedbar0() {
#if __has_builtin(__builtin_amdgcn_sched_barrier)
    __builtin_amdgcn_sched_barrier(0);
#endif
}
static __device__ __forceinline__ void rawbar() {
#if __has_builtin(__builtin_amdgcn_s_barrier)
    __builtin_amdgcn_s_barrier();
#else
    __syncthreads();
#endif
}

// ---------------- Kernel 1: fused pool(x,c2) + key conv + edge attention ----------------
// ea output pre-scaled by LOG2E.
__global__ __launch_bounds__(256) void prep_kernel(
    const float* __restrict__ x, const float* __restrict__ c2,
    const float* __restrict__ wq, const float* __restrict__ bq,
    const float* __restrict__ w1, const float* __restrict__ bnw, const float* __restrict__ bnb,
    const float* __restrict__ bnm, const float* __restrict__ bnv,
    const float* __restrict__ w2, const float* __restrict__ b2,
    unsigned short* __restrict__ kb, unsigned short* __restrict__ vb, float* __restrict__ ea) {

    __shared__ float lw1[OD_*2*C_];
    __shared__ float lwq[KD_*C_];
    __shared__ float xs[C_*33];
    __shared__ float c2s[C_*33];
    __shared__ float red[8][32];

    int tid = threadIdx.x;
    int b = blockIdx.x / 72;
    int m0 = (blockIdx.x % 72) * 32;

    for (int i = tid; i < OD_*2*C_; i += 256) lw1[i] = w1[i];
    for (int i = tid; i < KD_*C_; i += 256) lwq[i] = wq[i];
    for (int j = tid; j < 2048; j += 256) {
        int c = j >> 5, p = j & 31;
        int m = m0 + p;
        int hp = m / WP_, wp = m % WP_;
        size_t base = ((size_t)(b*C_ + c)*H_ + 2*hp)*W_ + 2*wp;
        const float* px = x + base;
        float mx = fmaxf(fmaxf(px[0], px[1]), fmaxf(px[W_], px[W_+1]));
        xs[c*33 + p] = mx;
        vb[(size_t)(b*C_ + c)*M_ + m] = f2bf(mx);
        const float* pc = c2 + base;
        c2s[c*33 + p] = fmaxf(fmaxf(pc[0], pc[1]), fmaxf(pc[W_], pc[W_+1]));
    }
    __syncthreads();

    int ml = tid & 31, oz = tid >> 5;
    int m = m0 + ml;

    float h[8] = {0,0,0,0,0,0,0,0};
    for (int c = 0; c < C_; c += 4) {
        float x0 = xs[c*33+ml], x1 = xs[(c+1)*33+ml], x2 = xs[(c+2)*33+ml], x3 = xs[(c+3)*33+ml];
        #pragma unroll
        for (int oi = 0; oi < 8; oi++) {
            const float4 wv = *(const float4*)&lwq[(oz*8 + oi)*C_ + c];
            h[oi] = fmaf(wv.x, x0, fmaf(wv.y, x1, fmaf(wv.z, x2, fmaf(wv.w, x3, h[oi]))));
        }
    }
    unsigned short tmp[8];
    #pragma unroll
    for (int oi = 0; oi < 8; oi++) tmp[oi] = f2bf(h[oi] + bq[oz*8 + oi]);
    *(uint4*)&kb[((size_t)b*M_ + m)*KD_ + oz*8] = *(const uint4*)tmp;

    float g[8] = {0,0,0,0,0,0,0,0};
    for (int c = 0; c < 2*C_; c += 4) {
        const float* srcb = (c < C_) ? &c2s[c*33] : &xs[(c - C_)*33];
        float x0 = srcb[ml], x1 = srcb[33+ml], x2 = srcb[66+ml], x3 = srcb[99+ml];
        #pragma unroll
        for (int oi = 0; oi < 8; oi++) {
            const float4 wv = *(const float4*)&lw1[(oz*8 + oi)*(2*C_) + c];
            g[oi] = fmaf(wv.x, x0, fmaf(wv.y, x1, fmaf(wv.z, x2, fmaf(wv.w, x3, g[oi]))));
        }
    }
    float z = 0.f;
    #pragma unroll
    for (int oi = 0; oi < 8; oi++) {
        int o = oz*8 + oi;
        float sc = bnw[o] * rsqrtf(bnv[o] + BN_EPS);
        float t = (g[oi] - bnm[o]) * sc + bnb[o];
        z += w2[o] * fmaxf(t, 0.f);
    }
    red[oz][ml] = z;
    __syncthreads();
    if (oz == 0) {
        float s = b2[0];
        #pragma unroll
        for (int i = 0; i < 8; i++) s += red[i][ml];
        ea[(size_t)b*M_ + m] = LOG2E / (1.f + __builtin_amdgcn_exp2f(-s * LOG2E));
    }
}

// ---------------- Kernel 2: query conv at full res -> bf16 [b][n][64] ----------------
__global__ __launch_bounds__(256) void qk_kernel(const float* __restrict__ in, const float* __restrict__ wq,
    const float* __restrict__ bq, unsigned short* __restrict__ outb) {
    __shared__ float lw[KD_*C_];
    for (int i = threadIdx.x; i < KD_*C_; i += 256) lw[i] = wq[i];
    __syncthreads();
    int ml = threadIdx.x & 31, oz = threadIdx.x >> 5;
    int pg = blockIdx.x * 32 + ml;
    float h[8] = {0,0,0,0,0,0,0,0};
    const float* src = in + ((size_t)(pg / N_))*C_*N_ + (pg % N_);
    for (int c = 0; c < C_; c += 4) {
        float x0 = src[(size_t)c*N_], x1 = src[(size_t)(c+1)*N_];
        float x2 = src[(size_t)(c+2)*N_], x3 = src[(size_t)(c+3)*N_];
        #pragma unroll
        for (int oi = 0; oi < 8; oi++) {
            const float4 wv = *(const float4*)&lw[(oz*8 + oi)*C_ + c];
            h[oi] = fmaf(wv.x, x0, fmaf(wv.y, x1, fmaf(wv.z, x2, fmaf(wv.w, x3, h[oi]))));
        }
    }
    unsigned short tmp[8];
    #pragma unroll
    for (int oi = 0; oi < 8; oi++) tmp[oi] = f2bf(h[oi] + bq[oz*8 + oi]);
    *(uint4*)&outb[(size_t)pg*KD_ + oz*8] = *(const uint4*)tmp;
}

// ---------------- Kernel 3: flash attention ----------------
// R5: counted-vmcnt deep pipeline (T3/T4). R2/R4 showed runtime scales with
// tile-steps/CU at ~1000cyc/step vs ~600cyc of issue work — the gap is
// __syncthreads()' vmcnt(0) drain waiting on the prefetch issued ~600cyc
// earlier. New loop: prefetch distance 2, per-tile {vmcnt(4); bar; ds_read
// frags; lgkmcnt(0); bar; STAGE(t+2); MFMA} — loads get ~2 tiles of slack,
// never drained to 0 in-loop. ea moved to LDS in prologue (an in-loop global
// load would make the compiler emit vmcnt(0) and kill the counting).
// LDS 41984B -> still 3 blocks/CU at QT=48/grid=768 (R2 residency).
__global__ __launch_bounds__(256, 3) void attn_kernel(
    const unsigned short* __restrict__ qb, const unsigned short* __restrict__ kb,
    const unsigned short* __restrict__ vb, const float* __restrict__ ea,
    const float* __restrict__ x, const float* __restrict__ gamma_p, float* __restrict__ out) {

    // dbuf: [k 8192 | v 8192] x2 = 32768 B, ea 9216 B -> 41984 B
    // epilogue overlay: o_red 2*48*68*4=26112 + l_red 768 = 26880 B (fits)
    __shared__ __align__(16) char smem[41984];

    int tid = threadIdx.x;
    int wave = tid >> 6, lane = tid & 63, quad = lane >> 4, l16 = lane & 15;
    int blk = blockIdx.x;
    int b = (blk & 7) >> 1;                       // batch pinned to XCD pair
    int n_base = ((blk & 1) * (QB_/2) + (blk >> 3)) * QT_;

    // Q B-frags: B[col = q = qi*16+l16][k = quad*8+j]
    bf16x8 qf[QI_][2];
    #pragma unroll
    for (int qi = 0; qi < QI_; qi++) {
        const unsigned short* qp = qb + ((size_t)b*N_ + n_base + qi*16 + l16)*KD_;
        qf[qi][0] = __builtin_bit_cast(bf16x8, *(const uint4*)(qp + quad*8));
        qf[qi][1] = __builtin_bit_cast(bf16x8, *(const uint4*)(qp + 32 + quad*8));
    }

    f32x4 o2[QI_][4]; // O^T partial: [qi][ct]; D: row=c=ct*16+quad*4+r, col=q=qi*16+l16
    f32x4 lacc[QI_];  // denominator partials via ones-MFMA (all D rows identical)
    #pragma unroll
    for (int qi = 0; qi < QI_; qi++) {
        lacc[qi] = (f32x4){0.f,0.f,0.f,0.f};
        #pragma unroll
        for (int ct = 0; ct < 4; ct++) o2[qi][ct] = (f32x4){0.f,0.f,0.f,0.f};
    }
    const short one_bf = (short)0x3F80;  // bf16 1.0
    short4v ones = (short4v){one_bf, one_bf, one_bf, one_bf};

    const unsigned short* kbB = kb + (size_t)b*M_*KD_;
    const unsigned short* vbB = vb + (size_t)b*C_*M_;
    const float* eaB = ea + (size_t)b*M_;

    // staging thread mapping: row = p*32 + (tid>>3), chunk = tid&7.
    int srow = tid >> 3;                    // 0..31
    int ksw  = ((tid & 7) ^ (srow & 7)) << 3;  // swizzled src offset (shorts)

    // DMA-stage one 64-m tile (K: 64x64 bf16 row-major; V: 64c x 64m bf16)
    // exactly 4 gl_lds per thread per call -> vmcnt counts in units of 4.
    auto STAGE = [&](int mb, char* kd, char* vd) {
        unsigned short* kds = (unsigned short*)kd;
        unsigned short* vds = (unsigned short*)vd;
        gl_lds16(kbB + (size_t)(mb + srow)*KD_      + ksw, kds + tid*8);
        gl_lds16(kbB + (size_t)(mb + srow + 32)*KD_ + ksw, kds + 2048 + tid*8);
        gl_lds16(vbB + (size_t)srow*M_      + mb + ksw, vds + tid*8);
        gl_lds16(vbB + (size_t)(srow+32)*M_ + mb + ksw, vds + 2048 + tid*8);
    };

    // ---- prologue: ea -> LDS (one-time), then stage tiles 0 and 1 ----
    {
        const f32x4* eaV = (const f32x4*)eaB;
        f32x4* eaL = (f32x4*)(smem + 32768);
        for (int i = tid; i < M_/4; i += 256) eaL[i] = eaV[i];  // compiler drains these
    }
    STAGE(0,  smem,          smem + 8192);
    STAGE(64, smem + 16384,  smem + 16384 + 8192);
    asm volatile("s_waitcnt lgkmcnt(0)" ::: "memory");   // ea ds_writes done (this wave)

    const float* lds_ea = (const float*)(smem + 32768);
    int xsw = l16 & 7;   // row&7 for all frag rows this lane touches

    for (int mt = 0; mt < NT_; mt++) {
        int cur = mt & 1;
        // t's 4 DMA ops done; t+1's 4 may remain in flight. NEVER vmcnt(0) mid-loop.
        if (mt < NT_ - 1) { asm volatile("s_waitcnt vmcnt(4)" ::: "memory"); }
        else             { asm volatile("s_waitcnt vmcnt(0)" ::: "memory"); }
        rawbar();                              // buf[cur] valid for all waves

        unsigned short* kc = (unsigned short*)(smem + cur*16384);
        unsigned short* vc = (unsigned short*)(smem + cur*16384 + 8192);

        // frag + ea reads (LDS only; swizzled chunk index: cg ^ (row&7))
        f32x4 e4 = *(const f32x4*)&lds_ea[mt*64 + wave*16 + quad*4];
        int krow = wave*16 + l16;
        bf16x8 kf0 = __builtin_bit_cast(bf16x8, *(const uint4*)(kc + krow*KD_ + (((quad  ) ^ xsw) << 3)));
        bf16x8 kf1 = __builtin_bit_cast(bf16x8, *(const uint4*)(kc + krow*KD_ + (((quad+4) ^ xsw) << 3)));
        short4v va[4];
        #pragma unroll
        for (int ct = 0; ct < 4; ct++)
            va[ct] = *(const short4v*)(vc + (ct*16 + l16)*64
                        + (((wave*2 + (quad>>1)) ^ xsw) << 3) + (quad&1)*4);

        asm volatile("s_waitcnt lgkmcnt(0)" ::: "memory");  // this wave's reads landed
        rawbar();                              // ALL waves done reading buf[cur]
        schedbar0();                           // pin STAGE below the release barrier

        if (mt < NT_ - 2) {
            char* nb = smem + cur*16384;       // buf[cur] now free -> stage t+2 into it
            STAGE((mt+2)*64, nb, nb + 8192);
        }

        // ---- register-only compute: no memory waits from here to loop end ----
        f32x4 st[QI_];
        setprio1();
        #pragma unroll
        for (int qi = 0; qi < QI_; qi++) {
            f32x4 z = (f32x4){0.f,0.f,0.f,0.f};
            z = __builtin_amdgcn_mfma_f32_16x16x32_bf16(kf0, qf[qi][0], z, 0, 0, 0);
            z = __builtin_amdgcn_mfma_f32_16x16x32_bf16(kf1, qf[qi][1], z, 0, 0, 0);
            st[qi] = z;
        }
        setprio0();

        // fixed-shift softmax numerators; packed cvt (v_cvt_pk_bf16_f32)
        short4v pk[QI_];
        #pragma unroll
        for (int qi = 0; qi < QI_; qi++) {
            f32x4 p;
            p[0] = __builtin_amdgcn_exp2f(fmaf(st[qi][0], e4[0], -SHIFT2));
            p[1] = __builtin_amdgcn_exp2f(fmaf(st[qi][1], e4[1], -SHIFT2));
            p[2] = __builtin_amdgcn_exp2f(fmaf(st[qi][2], e4[2], -SHIFT2));
            p[3] = __builtin_amdgcn_exp2f(fmaf(st[qi][3], e4[3], -SHIFT2));
            pk[qi] = __builtin_bit_cast(short4v, __builtin_convertvector(p, bf16x4));
        }

        // PV (A = V^T strip frag, B = P) + denominator via ones-A MFMA
        setprio1();
        #pragma unroll
        for (int ct = 0; ct < 4; ct++)
            #pragma unroll
            for (int qi = 0; qi < QI_; qi++)
                o2[qi][ct] = mfma16_bf16(va[ct], pk[qi], o2[qi][ct]);
        #pragma unroll
        for (int qi = 0; qi < QI_; qi++)
            lacc[qi] = mfma16_bf16(ones, pk[qi], lacc[qi]);
        setprio0();
        // no barrier here: next iteration's vmcnt+barrier is the hand-off
    }

    // ---- epilogue: cross-wave reduction of O^T partials and denominators ----
    // (last tile's release-barrier guarantees all waves finished reading LDS)
    float* o_red0 = (float*)smem;            // [48 q][68 c]
    float* o_red1 = o_red0 + QT_*68;
    float* l_red  = o_red1 + QT_*68;         // [4][48]

    if (lane < 16) {
        #pragma unroll
        for (int qi = 0; qi < QI_; qi++) l_red[wave*QT_ + qi*16 + l16] = lacc[qi][0];
    }
    if (wave < 2) {
        float* od = (wave == 0) ? o_red0 : o_red1;
        #pragma unroll
        for (int qi = 0; qi < QI_; qi++)
            #pragma unroll
            for (int ct = 0; ct < 4; ct++)
                *(f32x4*)&od[(qi*16 + l16)*68 + ct*16 + quad*4] = o2[qi][ct];
    }
    __syncthreads();
    if (wave >= 2) {
        float* od = (wave == 2) ? o_red0 : o_red1;
        #pragma unroll
        for (int qi = 0; qi < QI_; qi++)
            #pragma unroll
            for (int ct = 0; ct < 4; ct++) {
                f32x4* p = (f32x4*)&od[(qi*16 + l16)*68 + ct*16 + quad*4];
                *p += o2[qi][ct];
            }
    }
    __syncthreads();
    if (tid < QT_) {
        float s = (l_red[tid] + l_red[QT_ + tid]) + (l_red[2*QT_ + tid] + l_red[3*QT_ + tid]);
        l_red[tid] = 1.f / s;
    }
    __syncthreads();

    float gmm = gamma_p[0];
    int c = tid >> 2, q4 = tid & 3;
    const float* xrow = x + ((size_t)b*C_ + c)*N_ + n_base;
    float* orow = out + ((size_t)b*C_ + c)*N_ + n_base;
    #pragma unroll
    for (int i = 0; i < QI_; i++) {
        int q0 = q4*4 + i*16;
        float4 xv = *(const float4*)(xrow + q0);
        float4 ov;
        float v0 = (o_red0[(q0+0)*68 + c] + o_red1[(q0+0)*68 + c]) * l_red[q0+0];
        float v1 = (o_red0[(q0+1)*68 + c] + o_red1[(q0+1)*68 + c]) * l_red[q0+1];
        float v2 = (o_red0[(q0+2)*68 + c] + o_red1[(q0+2)*68 + c]) * l_red[q0+2];
        float v3 = (o_red0[(q0+3)*68 + c] + o_red1[(q0+3)*68 + c]) * l_red[q0+3];
        ov.x = fmaf(gmm, v0, xv.x);
        ov.y = fmaf(gmm, v1, xv.y);
        ov.z = fmaf(gmm, v2, xv.z);
        ov.w = fmaf(gmm, v3, xv.w);
        *(float4*)(orow + q0) = ov;
    }
}

extern "C" void kernel_launch(void* const* d_in, const int* in_sizes, int n_in,
                              void* d_out, int out_size, void* d_ws, size_t ws_size,
                              hipStream_t stream) {
    const float* c2    = (const float*)d_in[0];
    const float* x     = (const float*)d_in[1];
    const float* w_ea1 = (const float*)d_in[2];
    const float* bn_w  = (const float*)d_in[3];
    const float* bn_b  = (const float*)d_in[4];
    const float* bn_m  = (const float*)d_in[5];
    const float* bn_v  = (const float*)d_in[6];
    const float* w_ea2 = (const float*)d_in[7];
    const float* b_ea2 = (const float*)d_in[8];
    const float* w_q   = (const float*)d_in[9];
    const float* b_q   = (const float*)d_in[10];
    const float* gamma = (const float*)d_in[11];
    float* out = (float*)d_out;

    char* ws = (char*)d_ws;
    float* ea            = (float*)(ws + 0);                // 36864
    unsigned short* qb   = (unsigned short*)(ws + 36864);   // 4718592
    unsigned short* kb   = (unsigned short*)(ws + 4755456); // 1179648
    unsigned short* vb   = (unsigned short*)(ws + 5935104); // 1179648

    prep_kernel<<<dim3((B_*M_)/32), dim3(256), 0, stream>>>(x, c2, w_q, b_q,
        w_ea1, bn_w, bn_b, bn_m, bn_v, w_ea2, b_ea2, kb, vb, ea);
    qk_kernel<<<dim3((B_*N_)/32), dim3(256), 0, stream>>>(x, w_q, b_q, qb);
    attn_kernel<<<dim3(B_*QB_), dim3(256), 0, stream>>>(qb, kb, vb, ea, x, gamma, out);
}

// Round 6
// 160.629 us; speedup vs baseline: 1.6624x; 1.0156x over previous
//
#include <hip/hip_runtime.h>
#include <stdint.h>

#define B_ 4
#define C_ 64
#define H_ 96
#define W_ 96
#define HP_ 48
#define WP_ 48
#define N_ (H_*W_)      // 9216
#define M_ (HP_*WP_)    // 2304
#define KD_ 64
#define OD_ 64
#define BN_EPS 1e-5f
#define LOG2E 1.4426950408889634f
#define SHIFT2 28.853900817779268f   // 20 * LOG2E
#define QT_ 48                        // q-tile: 768 blocks = exactly 3/CU
#define QI_ (QT_/16)                  // 3 q-frags per block
#define QB_ (N_/QT_)                  // 192 q-tiles per batch
#define NT_ (M_/64)                   // 36 m-tiles (even — manual 2x unroll relies on it)

typedef __bf16 bf16_t;
typedef bf16_t bf16x8 __attribute__((ext_vector_type(8)));
typedef bf16_t bf16x4 __attribute__((ext_vector_type(4)));
typedef float f32x4 __attribute__((ext_vector_type(4)));
typedef short short4v __attribute__((ext_vector_type(4)));

static __device__ __forceinline__ unsigned short f2bf(float f) {
    unsigned int u = __builtin_bit_cast(unsigned int, f);
    u += 0x7fffu + ((u >> 16) & 1u);
    return (unsigned short)(u >> 16);
}

static __device__ __forceinline__ f32x4 mfma16_bf16(short4v a, short4v b, f32x4 c) {
#if __has_builtin(__builtin_amdgcn_mfma_f32_16x16x16bf16_1k)
    return __builtin_amdgcn_mfma_f32_16x16x16bf16_1k(a, b, c, 0, 0, 0);
#else
    return c;  // host pass only — never executed on device
#endif
}

// async global->LDS DMA, 16B per lane. LDS dest must be linear.
static __device__ __forceinline__ void gl_lds16(const unsigned short* g, unsigned short* l) {
#if __has_builtin(__builtin_amdgcn_global_load_lds)
    __builtin_amdgcn_global_load_lds(
        (const __attribute__((address_space(1))) unsigned int*)(const void*)g,
        (__attribute__((address_space(3))) unsigned int*)(void*)l, 16, 0, 0);
#endif
}

static __device__ __forceinline__ void setprio1() {
#if __has_builtin(__builtin_amdgcn_s_setprio)
    __builtin_amdgcn_s_setprio(1);
#endif
}
static __device__ __forceinline__ void setprio0() {
#if __has_builtin(__builtin_amdgcn_s_setprio)
    __builtin_amdgcn_s_setprio(0);
#endif
}
static __device__ __forceinline__ void schedbar0() {
#if __has_builtin(__builtin_amdgcn_sched_barrier)
    __builtin_amdgcn_sched_barrier(0);
#endif
}
static __device__ __forceinline__ void rawbar() {
#if __has_builtin(__builtin_amdgcn_s_barrier)
    __builtin_amdgcn_s_barrier();
#else
    __syncthreads();
#endif
}

// ---------------- Kernel 1: fused pool(x,c2) + key conv + edge attention ----------------
__global__ __launch_bounds__(256) void prep_kernel(
    const float* __restrict__ x, const float* __restrict__ c2,
    const float* __restrict__ wq, const float* __restrict__ bq,
    const float* __restrict__ w1, const float* __restrict__ bnw, const float* __restrict__ bnb,
    const float* __restrict__ bnm, const float* __restrict__ bnv,
    const float* __restrict__ w2, const float* __restrict__ b2,
    unsigned short* __restrict__ kb, unsigned short* __restrict__ vb, float* __restrict__ ea) {

    __shared__ float lw1[OD_*2*C_];
    __shared__ float lwq[KD_*C_];
    __shared__ float xs[C_*33];
    __shared__ float c2s[C_*33];
    __shared__ float red[8][32];

    int tid = threadIdx.x;
    int b = blockIdx.x / 72;
    int m0 = (blockIdx.x % 72) * 32;

    for (int i = tid; i < OD_*2*C_; i += 256) lw1[i] = w1[i];
    for (int i = tid; i < KD_*C_; i += 256) lwq[i] = wq[i];
    for (int j = tid; j < 2048; j += 256) {
        int c = j >> 5, p = j & 31;
        int m = m0 + p;
        int hp = m / WP_, wp = m % WP_;
        size_t base = ((size_t)(b*C_ + c)*H_ + 2*hp)*W_ + 2*wp;
        const float* px = x + base;
        float mx = fmaxf(fmaxf(px[0], px[1]), fmaxf(px[W_], px[W_+1]));
        xs[c*33 + p] = mx;
        vb[(size_t)(b*C_ + c)*M_ + m] = f2bf(mx);
        const float* pc = c2 + base;
        c2s[c*33 + p] = fmaxf(fmaxf(pc[0], pc[1]), fmaxf(pc[W_], pc[W_+1]));
    }
    __syncthreads();

    int ml = tid & 31, oz = tid >> 5;
    int m = m0 + ml;

    float h[8] = {0,0,0,0,0,0,0,0};
    for (int c = 0; c < C_; c += 4) {
        float x0 = xs[c*33+ml], x1 = xs[(c+1)*33+ml], x2 = xs[(c+2)*33+ml], x3 = xs[(c+3)*33+ml];
        #pragma unroll
        for (int oi = 0; oi < 8; oi++) {
            const float4 wv = *(const float4*)&lwq[(oz*8 + oi)*C_ + c];
            h[oi] = fmaf(wv.x, x0, fmaf(wv.y, x1, fmaf(wv.z, x2, fmaf(wv.w, x3, h[oi]))));
        }
    }
    unsigned short tmp[8];
    #pragma unroll
    for (int oi = 0; oi < 8; oi++) tmp[oi] = f2bf(h[oi] + bq[oz*8 + oi]);
    *(uint4*)&kb[((size_t)b*M_ + m)*KD_ + oz*8] = *(const uint4*)tmp;

    float g[8] = {0,0,0,0,0,0,0,0};
    for (int c = 0; c < 2*C_; c += 4) {
        const float* srcb = (c < C_) ? &c2s[c*33] : &xs[(c - C_)*33];
        float x0 = srcb[ml], x1 = srcb[33+ml], x2 = srcb[66+ml], x3 = srcb[99+ml];
        #pragma unroll
        for (int oi = 0; oi < 8; oi++) {
            const float4 wv = *(const float4*)&lw1[(oz*8 + oi)*(2*C_) + c];
            g[oi] = fmaf(wv.x, x0, fmaf(wv.y, x1, fmaf(wv.z, x2, fmaf(wv.w, x3, g[oi]))));
        }
    }
    float z = 0.f;
    #pragma unroll
    for (int oi = 0; oi < 8; oi++) {
        int o = oz*8 + oi;
        float sc = bnw[o] * rsqrtf(bnv[o] + BN_EPS);
        float t = (g[oi] - bnm[o]) * sc + bnb[o];
        z += w2[o] * fmaxf(t, 0.f);
    }
    red[oz][ml] = z;
    __syncthreads();
    if (oz == 0) {
        float s = b2[0];
        #pragma unroll
        for (int i = 0; i < 8; i++) s += red[i][ml];
        ea[(size_t)b*M_ + m] = LOG2E / (1.f + __builtin_amdgcn_exp2f(-s * LOG2E));
    }
}

// ---------------- Kernel 2: query conv at full res -> bf16 [b][n][64] ----------------
__global__ __launch_bounds__(256) void qk_kernel(const float* __restrict__ in, const float* __restrict__ wq,
    const float* __restrict__ bq, unsigned short* __restrict__ outb) {
    __shared__ float lw[KD_*C_];
    for (int i = threadIdx.x; i < KD_*C_; i += 256) lw[i] = wq[i];
    __syncthreads();
    int ml = threadIdx.x & 31, oz = threadIdx.x >> 5;
    int pg = blockIdx.x * 32 + ml;
    float h[8] = {0,0,0,0,0,0,0,0};
    const float* src = in + ((size_t)(pg / N_))*C_*N_ + (pg % N_);
    for (int c = 0; c < C_; c += 4) {
        float x0 = src[(size_t)c*N_], x1 = src[(size_t)(c+1)*N_];
        float x2 = src[(size_t)(c+2)*N_], x3 = src[(size_t)(c+3)*N_];
        #pragma unroll
        for (int oi = 0; oi < 8; oi++) {
            const float4 wv = *(const float4*)&lw[(oz*8 + oi)*C_ + c];
            h[oi] = fmaf(wv.x, x0, fmaf(wv.y, x1, fmaf(wv.z, x2, fmaf(wv.w, x3, h[oi]))));
        }
    }
    unsigned short tmp[8];
    #pragma unroll
    for (int oi = 0; oi < 8; oi++) tmp[oi] = f2bf(h[oi] + bq[oz*8 + oi]);
    *(uint4*)&outb[(size_t)pg*KD_ + oz*8] = *(const uint4*)tmp;
}

// ---------------- Kernel 3: flash attention ----------------
// R6: register-level 1-deep pipeline. R5 proved the DMA drain wasn't the
// stall; the per-step chain (ds_read -> lgkm -> QK -> exp -> PV) still ran
// inside each barrier interval. Now iteration t holds tile t's frags in
// REGISTERS and its body is: vmcnt(0)[free] -> bar -> STAGE(t+2) ->
// issue ds_reads(t+1, no wait) -> compute(t). LDS latency of t+1 and DMA of
// t+2 hide under compute(t); one barrier per step is the only serial sync.
// buf[t&1] is stage-safe after the t-top barrier because every wave read
// tile t (body t-1) BEFORE its compute(t-1), hence before this barrier.
// Frag double-buffer = two named structs (no runtime indexing, rule #20);
// raw s_barrier + memory-clobber + sched_barrier(0) fences (rule #18).
__global__ __launch_bounds__(256, 3) void attn_kernel(
    const unsigned short* __restrict__ qb, const unsigned short* __restrict__ kb,
    const unsigned short* __restrict__ vb, const float* __restrict__ ea,
    const float* __restrict__ x, const float* __restrict__ gamma_p, float* __restrict__ out) {

    // dbuf: [k 8192 | v 8192] x2 = 32768 B, ea 9216 B -> 41984 B
    // epilogue overlay: o_red 2*48*68*4=26112 + l_red 768 = 26880 B (fits)
    __shared__ __align__(16) char smem[41984];

    int tid = threadIdx.x;
    int wave = tid >> 6, lane = tid & 63, quad = lane >> 4, l16 = lane & 15;
    int blk = blockIdx.x;
    int b = (blk & 7) >> 1;                       // batch pinned to XCD pair
    int n_base = ((blk & 1) * (QB_/2) + (blk >> 3)) * QT_;

    // Q B-frags: B[col = q = qi*16+l16][k = quad*8+j]
    bf16x8 qf[QI_][2];
    #pragma unroll
    for (int qi = 0; qi < QI_; qi++) {
        const unsigned short* qp = qb + ((size_t)b*N_ + n_base + qi*16 + l16)*KD_;
        qf[qi][0] = __builtin_bit_cast(bf16x8, *(const uint4*)(qp + quad*8));
        qf[qi][1] = __builtin_bit_cast(bf16x8, *(const uint4*)(qp + 32 + quad*8));
    }

    f32x4 o2[QI_][4]; // O^T partial: [qi][ct]
    f32x4 lacc[QI_];  // denominator partials via ones-MFMA
    #pragma unroll
    for (int qi = 0; qi < QI_; qi++) {
        lacc[qi] = (f32x4){0.f,0.f,0.f,0.f};
        #pragma unroll
        for (int ct = 0; ct < 4; ct++) o2[qi][ct] = (f32x4){0.f,0.f,0.f,0.f};
    }
    const short one_bf = (short)0x3F80;  // bf16 1.0
    short4v ones = (short4v){one_bf, one_bf, one_bf, one_bf};

    const unsigned short* kbB = kb + (size_t)b*M_*KD_;
    const unsigned short* vbB = vb + (size_t)b*C_*M_;
    const float* eaB = ea + (size_t)b*M_;

    int srow = tid >> 3;                       // 0..31
    int ksw  = ((tid & 7) ^ (srow & 7)) << 3;  // swizzled src offset (shorts)

    auto STAGE = [&](int mb, char* kd, char* vd) {
        unsigned short* kds = (unsigned short*)kd;
        unsigned short* vds = (unsigned short*)vd;
        gl_lds16(kbB + (size_t)(mb + srow)*KD_      + ksw, kds + tid*8);
        gl_lds16(kbB + (size_t)(mb + srow + 32)*KD_ + ksw, kds + 2048 + tid*8);
        gl_lds16(vbB + (size_t)srow*M_      + mb + ksw, vds + tid*8);
        gl_lds16(vbB + (size_t)(srow+32)*M_ + mb + ksw, vds + 2048 + tid*8);
    };

    // ---- prologue: ea -> LDS, stage tiles 0+1, read frag set 0 ----
    {
        const f32x4* eaV = (const f32x4*)eaB;
        f32x4* eaL = (f32x4*)(smem + 32768);
        for (int i = tid; i < M_/4; i += 256) eaL[i] = eaV[i];
    }
    STAGE(0,  smem,          smem + 8192);
    STAGE(64, smem + 16384,  smem + 16384 + 8192);
    asm volatile("s_waitcnt vmcnt(4)" ::: "memory");   // tile0 DMA done
    asm volatile("s_waitcnt lgkmcnt(0)" ::: "memory"); // ea ds_writes done (per-wave)
    rawbar();
    asm volatile("" ::: "memory");

    const float* lds_ea = (const float*)(smem + 32768);
    int xsw = l16 & 7;
    int krow = wave*16 + l16;

    // frag double-buffer: two NAMED sets (constant field access only)
    struct FragSet { bf16x8 kf0, kf1; short4v va0, va1, va2, va3; f32x4 e4; };
    FragSet fA, fB;

    // read frag set for tile 0 into fA (from buf0)
    {
        unsigned short* kc = (unsigned short*)smem;
        unsigned short* vc = (unsigned short*)(smem + 8192);
        fA.e4  = *(const f32x4*)&lds_ea[0*64 + wave*16 + quad*4];
        fA.kf0 = __builtin_bit_cast(bf16x8, *(const uint4*)(kc + krow*KD_ + (((quad  ) ^ xsw) << 3)));
        fA.kf1 = __builtin_bit_cast(bf16x8, *(const uint4*)(kc + krow*KD_ + (((quad+4) ^ xsw) << 3)));
        fA.va0 = *(const short4v*)(vc + (0*16 + l16)*64 + (((wave*2 + (quad>>1)) ^ xsw) << 3) + (quad&1)*4);
        fA.va1 = *(const short4v*)(vc + (1*16 + l16)*64 + (((wave*2 + (quad>>1)) ^ xsw) << 3) + (quad&1)*4);
        fA.va2 = *(const short4v*)(vc + (2*16 + l16)*64 + (((wave*2 + (quad>>1)) ^ xsw) << 3) + (quad&1)*4);
        fA.va3 = *(const short4v*)(vc + (3*16 + l16)*64 + (((wave*2 + (quad>>1)) ^ xsw) << 3) + (quad&1)*4);
    }

// one pipeline step: compute tile T_ from CUR; prefetch T_+1 frags into NXT
#define ATTN_STEP(T_, CUR, NXT)                                                        \
    {                                                                                  \
        const int t_ = (T_);                                                           \
        if (t_ < NT_ - 1) {                                                            \
            asm volatile("s_waitcnt vmcnt(0)" ::: "memory");  /* tile t_+1 DMA done */ \
            schedbar0();                                                               \
            rawbar();                               /* acquire buf[(t_+1)&1], release buf[t_&1] */ \
            asm volatile("" ::: "memory");                                             \
            schedbar0();                                                               \
            if (t_ + 2 < NT_) {                                                        \
                char* nb = smem + (t_ & 1) * 16384;                                    \
                STAGE((t_ + 2) * 64, nb, nb + 8192);                                   \
            }                                                                          \
            unsigned short* kc_ = (unsigned short*)(smem + ((t_ + 1) & 1) * 16384);    \
            unsigned short* vc_ = (unsigned short*)(smem + ((t_ + 1) & 1) * 16384 + 8192); \
            NXT.e4  = *(const f32x4*)&lds_ea[(t_ + 1)*64 + wave*16 + quad*4];          \
            NXT.kf0 = __builtin_bit_cast(bf16x8, *(const uint4*)(kc_ + krow*KD_ + (((quad  ) ^ xsw) << 3))); \
            NXT.kf1 = __builtin_bit_cast(bf16x8, *(const uint4*)(kc_ + krow*KD_ + (((quad+4) ^ xsw) << 3))); \
            NXT.va0 = *(const short4v*)(vc_ + (0*16 + l16)*64 + (((wave*2 + (quad>>1)) ^ xsw) << 3) + (quad&1)*4); \
            NXT.va1 = *(const short4v*)(vc_ + (1*16 + l16)*64 + (((wave*2 + (quad>>1)) ^ xsw) << 3) + (quad&1)*4); \
            NXT.va2 = *(const short4v*)(vc_ + (2*16 + l16)*64 + (((wave*2 + (quad>>1)) ^ xsw) << 3) + (quad&1)*4); \
            NXT.va3 = *(const short4v*)(vc_ + (3*16 + l16)*64 + (((wave*2 + (quad>>1)) ^ xsw) << 3) + (quad&1)*4); \
            schedbar0();                                                               \
            asm volatile("s_waitcnt lgkmcnt(7)" ::: "memory"); /* CUR reads landed */  \
            schedbar0();                                                               \
        } else {                                                                       \
            schedbar0();                                                               \
            asm volatile("s_waitcnt lgkmcnt(0)" ::: "memory"); /* last frag set */     \
            schedbar0();                                                               \
        }                                                                              \
        /* ---- compute tile t_ from CUR (register-only) ---- */                       \
        f32x4 st[QI_];                                                                 \
        setprio1();                                                                    \
        _Pragma("unroll")                                                              \
        for (int qi = 0; qi < QI_; qi++) {                                             \
            f32x4 z = (f32x4){0.f,0.f,0.f,0.f};                                        \
            z = __builtin_amdgcn_mfma_f32_16x16x32_bf16(CUR.kf0, qf[qi][0], z, 0, 0, 0); \
            z = __builtin_amdgcn_mfma_f32_16x16x32_bf16(CUR.kf1, qf[qi][1], z, 0, 0, 0); \
            st[qi] = z;                                                                \
        }                                                                              \
        setprio0();                                                                    \
        short4v pk[QI_];                                                               \
        _Pragma("unroll")                                                              \
        for (int qi = 0; qi < QI_; qi++) {                                             \
            f32x4 p;                                                                   \
            p[0] = __builtin_amdgcn_exp2f(fmaf(st[qi][0], CUR.e4[0], -SHIFT2));        \
            p[1] = __builtin_amdgcn_exp2f(fmaf(st[qi][1], CUR.e4[1], -SHIFT2));        \
            p[2] = __builtin_amdgcn_exp2f(fmaf(st[qi][2], CUR.e4[2], -SHIFT2));        \
            p[3] = __builtin_amdgcn_exp2f(fmaf(st[qi][3], CUR.e4[3], -SHIFT2));        \
            pk[qi] = __builtin_bit_cast(short4v, __builtin_convertvector(p, bf16x4));  \
        }                                                                              \
        setprio1();                                                                    \
        _Pragma("unroll")                                                              \
        for (int qi = 0; qi < QI_; qi++) {                                             \
            o2[qi][0] = mfma16_bf16(CUR.va0, pk[qi], o2[qi][0]);                       \
            o2[qi][1] = mfma16_bf16(CUR.va1, pk[qi], o2[qi][1]);                       \
            o2[qi][2] = mfma16_bf16(CUR.va2, pk[qi], o2[qi][2]);                       \
            o2[qi][3] = mfma16_bf16(CUR.va3, pk[qi], o2[qi][3]);                       \
            lacc[qi]  = mfma16_bf16(ones,    pk[qi], lacc[qi]);                        \
        }                                                                              \
        setprio0();                                                                    \
    }

    for (int t = 0; t < NT_; t += 2) {
        ATTN_STEP(t,     fA, fB);
        ATTN_STEP(t + 1, fB, fA);
    }
#undef ATTN_STEP

    __syncthreads();   // all waves done with LDS K/V buffers before overlay

    // ---- epilogue: cross-wave reduction of O^T partials and denominators ----
    float* o_red0 = (float*)smem;            // [48 q][68 c]
    float* o_red1 = o_red0 + QT_*68;
    float* l_red  = o_red1 + QT_*68;         // [4][48]

    if (lane < 16) {
        #pragma unroll
        for (int qi = 0; qi < QI_; qi++) l_red[wave*QT_ + qi*16 + l16] = lacc[qi][0];
    }
    if (wave < 2) {
        float* od = (wave == 0) ? o_red0 : o_red1;
        #pragma unroll
        for (int qi = 0; qi < QI_; qi++)
            #pragma unroll
            for (int ct = 0; ct < 4; ct++)
                *(f32x4*)&od[(qi*16 + l16)*68 + ct*16 + quad*4] = o2[qi][ct];
    }
    __syncthreads();
    if (wave >= 2) {
        float* od = (wave == 2) ? o_red0 : o_red1;
        #pragma unroll
        for (int qi = 0; qi < QI_; qi++)
            #pragma unroll
            for (int ct = 0; ct < 4; ct++) {
                f32x4* p = (f32x4*)&od[(qi*16 + l16)*68 + ct*16 + quad*4];
                *p += o2[qi][ct];
            }
    }
    __syncthreads();
    if (tid < QT_) {
        float s = (l_red[tid] + l_red[QT_ + tid]) + (l_red[2*QT_ + tid] + l_red[3*QT_ + tid]);
        l_red[tid] = 1.f / s;
    }
    __syncthreads();

    float gmm = gamma_p[0];
    int c = tid >> 2, q4 = tid & 3;
    const float* xrow = x + ((size_t)b*C_ + c)*N_ + n_base;
    float* orow = out + ((size_t)b*C_ + c)*N_ + n_base;
    #pragma unroll
    for (int i = 0; i < QI_; i++) {
        int q0 = q4*4 + i*16;
        float4 xv = *(const float4*)(xrow + q0);
        float4 ov;
        float v0 = (o_red0[(q0+0)*68 + c] + o_red1[(q0+0)*68 + c]) * l_red[q0+0];
        float v1 = (o_red0[(q0+1)*68 + c] + o_red1[(q0+1)*68 + c]) * l_red[q0+1];
        float v2 = (o_red0[(q0+2)*68 + c] + o_red1[(q0+2)*68 + c]) * l_red[q0+2];
        float v3 = (o_red0[(q0+3)*68 + c] + o_red1[(q0+3)*68 + c]) * l_red[q0+3];
        ov.x = fmaf(gmm, v0, xv.x);
        ov.y = fmaf(gmm, v1, xv.y);
        ov.z = fmaf(gmm, v2, xv.z);
        ov.w = fmaf(gmm, v3, xv.w);
        *(float4*)(orow + q0) = ov;
    }
}

extern "C" void kernel_launch(void* const* d_in, const int* in_sizes, int n_in,
                              void* d_out, int out_size, void* d_ws, size_t ws_size,
                              hipStream_t stream) {
    const float* c2    = (const float*)d_in[0];
    const float* x     = (const float*)d_in[1];
    const float* w_ea1 = (const float*)d_in[2];
    const float* bn_w  = (const float*)d_in[3];
    const float* bn_b  = (const float*)d_in[4];
    const float* bn_m  = (const float*)d_in[5];
    const float* bn_v  = (const float*)d_in[6];
    const float* w_ea2 = (const float*)d_in[7];
    const float* b_ea2 = (const float*)d_in[8];
    const float* w_q   = (const float*)d_in[9];
    const float* b_q   = (const float*)d_in[10];
    const float* gamma = (const float*)d_in[11];
    float* out = (float*)d_out;

    char* ws = (char*)d_ws;
    float* ea            = (float*)(ws + 0);                // 36864
    unsigned short* qb   = (unsigned short*)(ws + 36864);   // 4718592
    unsigned short* kb   = (unsigned short*)(ws + 4755456); // 1179648
    unsigned short* vb   = (unsigned short*)(ws + 5935104); // 1179648

    prep_kernel<<<dim3((B_*M_)/32), dim3(256), 0, stream>>>(x, c2, w_q, b_q,
        w_ea1, bn_w, bn_b, bn_m, bn_v, w_ea2, b_ea2, kb, vb, ea);
    qk_kernel<<<dim3((B_*N_)/32), dim3(256), 0, stream>>>(x, w_q, b_q, qb);
    attn_kernel<<<dim3(B_*QB_), dim3(256), 0, stream>>>(qb, kb, vb, ea, x, gamma, out);
}